// Round 1
// baseline (458.788 us; speedup 1.0000x reference)
//
#include <hip/hip_runtime.h>

// 2-layer LSTM (B=4096, T=256, I=38, H1=50, H2=15) + FC(15->14) on last step.
// Strategy: f16-input MFMA (fp32 accum) for all gate GEMMs, fp32 state update.
// One block = 16 sequences, 4 waves; weights register-resident as B-fragments.

typedef _Float16 f16x8 __attribute__((ext_vector_type(8)));
typedef _Float16 f16x4 __attribute__((ext_vector_type(4)));
typedef float    f32x4 __attribute__((ext_vector_type(4)));

#if __has_builtin(__builtin_amdgcn_exp2f)
#define DEV_EXP2(x) __builtin_amdgcn_exp2f(x)
#else
#define DEV_EXP2(x) exp2f(x)
#endif
#if __has_builtin(__builtin_amdgcn_rcpf)
#define DEV_RCP(x) __builtin_amdgcn_rcpf(x)
#else
#define DEV_RCP(x) (1.0f/(x))
#endif

#define I1 38
#define H1 50
#define H2 15
#define NC 14
#define TSTEPS 256
#define SB 16          // sequences per block (= MFMA M)
#define XS 104         // f16 row stride of xh buffers (16B aligned, bank-friendly)
#define P1C 208        // padded layer-1 gate columns (13 tiles x 16)
#define P2C 64         // padded layer-2 gate columns (4 tiles x 16)
#define WINF 304       // f16 per seq per window = 8 steps * 38

__device__ __forceinline__ float sigm(float v) {
  return DEV_RCP(1.f + DEV_EXP2(-1.442695040888963f * v));
}
__device__ __forceinline__ float tanh_f(float v) {
  // tanh(v) = 1 - 2/(exp(2v)+1); exact at +-inf, no NaN for finite v
  return 1.f - 2.f * DEV_RCP(1.f + DEV_EXP2(2.885390081777927f * v));
}

__launch_bounds__(256, 1)
__global__ void lstm2_fused(const float* __restrict__ x,
                            const float* __restrict__ w_ih1, const float* __restrict__ w_hh1,
                            const float* __restrict__ b_ih1, const float* __restrict__ b_hh1,
                            const float* __restrict__ w_ih2, const float* __restrict__ w_hh2,
                            const float* __restrict__ b_ih2, const float* __restrict__ b_hh2,
                            const float* __restrict__ w_fc, const float* __restrict__ b_fc,
                            float* __restrict__ out)
{
  // xh1 row (per seq, f16): [ x_t (38) | h1 (50) | zeros (8) | pad ]  K1 = 96
  // xh2 row (per seq, f16): [ h1 (50) | h2 (15) | zeros (31) | pad ] K2 = 96
  __shared__ __align__(16) _Float16 s_xh1[SB][XS];
  __shared__ __align__(16) _Float16 s_xh2[SB][XS];
  __shared__ __align__(16) _Float16 s_win[2][SB * WINF];   // x window, 8 steps, f16
  __shared__ __align__(16) float s_pre1[SB][P1C];
  __shared__ __align__(16) float s_pre2[SB][P2C];
  __shared__ __align__(16) float s_bias1[P1C];
  __shared__ __align__(16) float s_bias2[P2C];

  const int tid  = threadIdx.x;
  const int wv   = tid >> 6;      // wave 0..3
  const int lane = tid & 63;
  const int lm   = lane & 15;     // A-row (seq) / D-col (gate row) index
  const int lk   = lane >> 4;     // k-chunk / m-group index
  const int blk  = blockIdx.x;
  const float* xblk = x + (size_t)blk * SB * TSTEPS * I1;

  // ---- init LDS: zero states (h=0), biases reordered to r' = 4*unit + gate ----
  for (int i = tid; i < SB * XS; i += 256) {
    ((_Float16*)s_xh1)[i] = (_Float16)0.f;
    ((_Float16*)s_xh2)[i] = (_Float16)0.f;
  }
  if (tid < P1C) {
    int j = tid >> 2, g = tid & 3;
    s_bias1[tid] = (j < H1) ? (b_ih1[g*H1 + j] + b_hh1[g*H1 + j]) : 0.f;
  }
  if (tid < P2C) {
    int j = tid >> 2, g = tid & 3;
    s_bias2[tid] = (j < H2) ? (b_ih2[g*H2 + j] + b_hh2[g*H2 + j]) : 0.f;
  }

  // ---- register-resident B fragments (weights), rows r' = 4j+g, k=[ih|hh|0] ----
  // L1: wave wv owns tiles {wv, wv+4, wv+8} and (wv==0) tile 12.
  f16x8 B1[4][3];
  #pragma unroll
  for (int i = 0; i < 4; ++i) {
    const int  tile  = (i < 3) ? (wv + 4*i) : 12;
    const bool valid = (i < 3) || (wv == 0);
    const int  r = tile*16 + lm;
    const int  j = r >> 2, g = r & 3;
    #pragma unroll
    for (int ks = 0; ks < 3; ++ks) {
      f16x8 v;
      #pragma unroll
      for (int e = 0; e < 8; ++e) {
        int k = ks*32 + lk*8 + e;
        float val = 0.f;
        if (valid && j < H1) {
          if (k < I1)            val = w_ih1[(g*H1 + j)*I1 + k];
          else if (k < I1 + H1)  val = w_hh1[(g*H1 + j)*H1 + (k - I1)];
        }
        v[e] = (_Float16)val;
      }
      B1[i][ks] = v;
    }
  }
  // L2: wave wv owns tile wv.
  f16x8 B2[3];
  {
    const int r = wv*16 + lm;
    const int j = r >> 2, g = r & 3;
    #pragma unroll
    for (int ks = 0; ks < 3; ++ks) {
      f16x8 v;
      #pragma unroll
      for (int e = 0; e < 8; ++e) {
        int k = ks*32 + lk*8 + e;
        float val = 0.f;
        if (j < H2) {
          if (k < H1)            val = w_ih2[(g*H2 + j)*H1 + k];
          else if (k < H1 + H2)  val = w_hh2[(g*H2 + j)*H2 + (k - H1)];
        }
        v[e] = (_Float16)val;
      }
      B2[ks] = v;
    }
  }

  // ---- x window loader: 16 seqs x 8 steps x 38 f32 -> f16 LDS (coalesced) ----
  auto load_window = [&](int t0, int buf) {
    #pragma unroll
    for (int it = 0; it < 5; ++it) {
      int c = it*256 + tid;            // float4 chunk id, 76 per seq
      if (c < SB * 76) {
        int s   = c / 76;
        int rem = (c % 76) * 4;        // f32 offset within seq-window
        const float4 v = *(const float4*)(xblk + (size_t)s*(TSTEPS*I1) + t0*I1 + rem);
        f16x4 h;
        h[0] = (_Float16)v.x; h[1] = (_Float16)v.y;
        h[2] = (_Float16)v.z; h[3] = (_Float16)v.w;
        *(f16x4*)&s_win[buf][s*WINF + rem] = h;
      }
    }
  };
  // copy x_t from window into xh1[.., 0..37]
  auto copy_x = [&](int t) {
    int buf = (t >> 3) & 1;
    int tw  = t & 7;
    #pragma unroll
    for (int it = 0; it < 3; ++it) {
      int e = it*256 + tid;
      if (e < SB * I1) {
        int s = e / I1, k = e % I1;
        s_xh1[s][k] = s_win[buf][s*WINF + tw*I1 + k];
      }
    }
  };

  load_window(0, 0);
  load_window(8, 1);
  __syncthreads();          // also drains the window loads
  copy_x(0);
  __syncthreads();

  float c1[4] = {0.f, 0.f, 0.f, 0.f};   // cell state L1: pair p = it*256+tid -> (s,u)
  float c2 = 0.f;                       // cell state L2: tid<240 -> (s,u)

  for (int t = 0; t < TSTEPS; ++t) {
    // ---------- layer-1 gate GEMM: pre1[s][r'] = xh1 . W1[r'] ----------
    f32x4 acc[4];
    #pragma unroll
    for (int i = 0; i < 4; ++i) acc[i] = (f32x4){0.f, 0.f, 0.f, 0.f};
    #pragma unroll
    for (int ks = 0; ks < 3; ++ks) {
      f16x8 a = *(const f16x8*)&s_xh1[lm][ks*32 + lk*8];
      #pragma unroll
      for (int i = 0; i < 4; ++i) {
        if (i < 3 || wv == 0)
          acc[i] = __builtin_amdgcn_mfma_f32_16x16x32_f16(a, B1[i][ks], acc[i], 0, 0, 0);
      }
    }
    #pragma unroll
    for (int i = 0; i < 4; ++i) {
      if (i < 3 || wv == 0) {
        int col = ((i < 3) ? (wv + 4*i) : 12)*16 + lm;
        #pragma unroll
        for (int m = 0; m < 4; ++m) s_pre1[lk*4 + m][col] = acc[i][m];
      }
    }
    __syncthreads();

    // ---------- layer-1 state update (800 (s,u) pairs over 256 threads) ----------
    #pragma unroll
    for (int it = 0; it < 4; ++it) {
      int p = it*256 + tid;
      if (p < SB * H1) {
        int s = p / H1, u = p % H1;
        f32x4 pre = *(const f32x4*)&s_pre1[s][4*u];
        f32x4 bs  = *(const f32x4*)&s_bias1[4*u];
        float ig = sigm  (pre[0] + bs[0]);
        float fg = sigm  (pre[1] + bs[1]);
        float gg = tanh_f(pre[2] + bs[2]);
        float og = sigm  (pre[3] + bs[3]);
        float c = fg * c1[it] + ig * gg;
        c1[it] = c;
        float h = og * tanh_f(c);
        _Float16 hh = (_Float16)h;
        s_xh1[s][I1 + u] = hh;   // h1 for next-step L1
        s_xh2[s][u]      = hh;   // h1 input for this-step L2
      }
    }
    __syncthreads();

    // ---------- layer-2 gate GEMM ----------
    f32x4 acc2 = (f32x4){0.f, 0.f, 0.f, 0.f};
    #pragma unroll
    for (int ks = 0; ks < 3; ++ks) {
      f16x8 a = *(const f16x8*)&s_xh2[lm][ks*32 + lk*8];
      acc2 = __builtin_amdgcn_mfma_f32_16x16x32_f16(a, B2[ks], acc2, 0, 0, 0);
    }
    {
      int col = wv*16 + lm;
      #pragma unroll
      for (int m = 0; m < 4; ++m) s_pre2[lk*4 + m][col] = acc2[m];
    }
    __syncthreads();

    // ---------- layer-2 update + stage next x + issue next window ----------
    if (tid < SB * H2) {
      int s = tid / H2, u = tid % H2;
      f32x4 pre = *(const f32x4*)&s_pre2[s][4*u];
      f32x4 bs  = *(const f32x4*)&s_bias2[4*u];
      float ig = sigm  (pre[0] + bs[0]);
      float fg = sigm  (pre[1] + bs[1]);
      float gg = tanh_f(pre[2] + bs[2]);
      float og = sigm  (pre[3] + bs[3]);
      float c = fg * c2 + ig * gg;
      c2 = c;
      float h = og * tanh_f(c);
      s_xh2[s][H1 + u] = (_Float16)h;
    }
    int tt = t + 1;
    if (tt < TSTEPS) {
      copy_x(tt);
      if ((tt & 7) == 0 && (tt + 8) < TSTEPS)
        load_window(tt + 8, ((tt + 8) >> 3) & 1);
    }
    __syncthreads();
  }

  // ---------- FC on last h2 ----------
  if (tid < SB * NC) {
    int s = tid / NC, n = tid % NC;
    float accf = b_fc[n];
    #pragma unroll
    for (int u = 0; u < H2; ++u)
      accf += (float)s_xh2[s][H1 + u] * w_fc[n*H2 + u];
    out[((size_t)blk*SB + s)*NC + n] = accf;
  }
}

extern "C" void kernel_launch(void* const* d_in, const int* in_sizes, int n_in,
                              void* d_out, int out_size, void* d_ws, size_t ws_size,
                              hipStream_t stream) {
  (void)n_in; (void)d_ws; (void)ws_size; (void)out_size;
  const float* x     = (const float*)d_in[0];
  const float* w_ih1 = (const float*)d_in[1];
  const float* w_hh1 = (const float*)d_in[2];
  const float* b_ih1 = (const float*)d_in[3];
  const float* b_hh1 = (const float*)d_in[4];
  const float* w_ih2 = (const float*)d_in[5];
  const float* w_hh2 = (const float*)d_in[6];
  const float* b_ih2 = (const float*)d_in[7];
  const float* b_hh2 = (const float*)d_in[8];
  const float* w_fc  = (const float*)d_in[9];
  const float* b_fc  = (const float*)d_in[10];
  float* out = (float*)d_out;

  const int B = in_sizes[0] / (TSTEPS * I1);   // 4096
  dim3 grid(B / SB), block(256);
  lstm2_fused<<<grid, block, 0, stream>>>(x, w_ih1, w_hh1, b_ih1, b_hh1,
                                          w_ih2, w_hh2, b_ih2, b_hh2,
                                          w_fc, b_fc, out);
}

// Round 2
// 362.541 us; speedup vs baseline: 1.2655x; 1.2655x over previous
//
#include <hip/hip_runtime.h>

// 2-layer LSTM (B=4096, T=256, I=38, H1=50, H2=15) + FC on last step.
// One block = 16 seqs (MFMA M=16), 4 waves. Unified A = [x_t|h1(t-1)|h2(t-2)]
// (K=128), gate-major B tiles -> lane-local in-register LSTM update.
// One barrier per step; L2 pipelined one step behind L1.

typedef _Float16 f16x8 __attribute__((ext_vector_type(8)));
typedef float    f32x4 __attribute__((ext_vector_type(4)));

#if __has_builtin(__builtin_amdgcn_exp2f)
#define DEV_EXP2(x) __builtin_amdgcn_exp2f(x)
#else
#define DEV_EXP2(x) exp2f(x)
#endif
#if __has_builtin(__builtin_amdgcn_rcpf)
#define DEV_RCP(x) __builtin_amdgcn_rcpf(x)
#else
#define DEV_RCP(x) (1.0f/(x))
#endif

#define I1 38
#define H1 50
#define H2 15
#define NC 14
#define TT 256
#define SB 16
// A-row layout (f16): [x:0..37 | h1:38..87 | h2:88..102 | zero:103..127 | pad:128..135]
#define XS 136

__device__ __forceinline__ float sigm(float v) {
  return DEV_RCP(1.f + DEV_EXP2(-1.442695040888963f * v));
}
__device__ __forceinline__ float tanh_f(float v) {
  return 1.f - 2.f * DEV_RCP(1.f + DEV_EXP2(2.885390081777927f * v));
}

__launch_bounds__(256, 1)
__global__ void lstm2_fused(const float* __restrict__ x,
                            const float* __restrict__ w_ih1, const float* __restrict__ w_hh1,
                            const float* __restrict__ b_ih1, const float* __restrict__ b_hh1,
                            const float* __restrict__ w_ih2, const float* __restrict__ w_hh2,
                            const float* __restrict__ b_ih2, const float* __restrict__ b_hh2,
                            const float* __restrict__ w_fc, const float* __restrict__ b_fc,
                            float* __restrict__ out)
{
  __shared__ __align__(16) _Float16 bufA[2][SB][XS];

  const int tid  = threadIdx.x;
  const int wv   = tid >> 6;
  const int lane = tid & 63;
  const int lm   = lane & 15;     // A-row (seq) for reads / B-col (unit) for weights
  const int lk   = lane >> 4;     // k-chunk group; C rows = 4*lk+m
  const int blk  = blockIdx.x;
  const float* xblk = x + (size_t)blk * SB * TT * I1;

  const bool isw2 = (wv == 2), isw3 = (wv == 3);

  // ---- zero both A buffers (pads/h-regions must start 0) ----
  for (int i = tid; i < 2*SB*XS; i += 256) ((_Float16*)bufA)[i] = (_Float16)0.f;

  // ---- slot0 lane->column params (ublock type = wv) ----
  // wv 0..2: L1 units wv*16+lm ; wv3: lm<2 -> L1 48+lm, lm>=2 -> L2 lm-2
  bool isl2_0; int idx0, dest0;
  if (wv <= 2) { isl2_0 = false; idx0 = wv*16 + lm; dest0 = 38 + idx0; }
  else         { isl2_0 = (lm >= 2); idx0 = isl2_0 ? (lm - 2) : (48 + lm); dest0 = 86 + lm; }
  // slot1 (wv2 only): L2 unit 14, valid in col lm==0
  const bool val1 = isw2 && (lm == 0);

  // ---- weight element fetch (unified-k indexing) ----
  auto welem = [&](bool isl2, bool valid, int idx, int g, int k) -> _Float16 {
    float v = 0.f;
    if (valid) {
      if (!isl2) {
        if (k < I1)               v = w_ih1[(g*H1 + idx)*I1 + k];
        else if (k < I1 + H1)     v = w_hh1[(g*H1 + idx)*H1 + (k - I1)];
      } else {
        if (k >= I1 && k < I1+H1)           v = w_ih2[(g*H2 + idx)*H1 + (k - I1)];
        else if (k >= I1+H1 && k < I1+H1+H2) v = w_hh2[(g*H2 + idx)*H2 + (k - I1 - H1)];
      }
    }
    return (_Float16)v;
  };

  // ---- register-resident B fragments ----
  f16x8 WA[4][4];
  #pragma unroll
  for (int g = 0; g < 4; ++g) {
    #pragma unroll
    for (int ks = 0; ks < 4; ++ks) {
      f16x8 v;
      #pragma unroll
      for (int e = 0; e < 8; ++e) v[e] = welem(isl2_0, true, idx0, g, ks*32 + lk*8 + e);
      WA[g][ks] = v;
    }
  }
  f16x8 WB[4][3];   // slot1: ks = 1..3
  #pragma unroll
  for (int g = 0; g < 4; ++g) {
    #pragma unroll
    for (int j = 0; j < 3; ++j) {
      f16x8 v;
      #pragma unroll
      for (int e = 0; e < 8; ++e) v[e] = welem(true, val1, 14, g, (j+1)*32 + lk*8 + e);
      WB[g][j] = v;
    }
  }

  // ---- biases (pre-seeded into MFMA C) ----
  float bias0[4], bias1[4];
  #pragma unroll
  for (int g = 0; g < 4; ++g) {
    bias0[g] = isl2_0 ? (b_ih2[g*H2 + idx0] + b_hh2[g*H2 + idx0])
                      : (b_ih1[g*H1 + idx0] + b_hh1[g*H1 + idx0]);
    bias1[g] = val1 ? (b_ih2[g*H2 + 14] + b_hh2[g*H2 + 14]) : 0.f;
  }

  // ---- x prefetch mapping: 608 f32/step over 256 threads ----
  const int e0 = tid, e1 = tid + 256, e2 = tid + 512;
  const int s0 = e0 / I1, k0 = e0 % I1;
  const int s1 = e1 / I1, k1 = e1 % I1;
  const int s2 = e2 / I1, k2 = e2 % I1;
  const bool v2 = (e2 < SB*I1);
  const int gb0 = s0*TT*I1 + k0, gb1 = s1*TT*I1 + k1, gb2 = v2 ? (s2*TT*I1 + k2) : 0;
  const int lb0 = s0*XS + k0,    lb1 = s1*XS + k1,    lb2 = v2 ? (s2*XS + k2) : 0;

  __syncthreads();          // zeros visible
  {                         // stage x(0) into buf[0]
    _Float16* b0 = &bufA[0][0][0];
    b0[lb0] = (_Float16)xblk[gb0];
    b0[lb1] = (_Float16)xblk[gb1];
    if (v2) b0[lb2] = (_Float16)xblk[gb2];
  }
  __syncthreads();

  float c0[4] = {0.f,0.f,0.f,0.f};   // slot0 cell state (4 seqs per lane)
  float c1[4] = {0.f,0.f,0.f,0.f};   // slot1 cell state

  for (int t = 0; t <= TT; ++t) {
    _Float16* cur = &bufA[t & 1][0][0];
    _Float16* nxt = &bufA[(t & 1) ^ 1][0][0];

    // T14: issue x(t+1) loads early, consume at step end
    const bool px = (t + 1 < TT);
    float xr0 = 0.f, xr1 = 0.f, xr2 = 0.f;
    if (px) {
      const int go = (t + 1) * I1;
      xr0 = xblk[gb0 + go];
      xr1 = xblk[gb1 + go];
      if (v2) xr2 = xblk[gb2 + go];
    }

    // A fragments (perfect 8-group bank spread at 272B row stride)
    f16x8 a[4];
    #pragma unroll
    for (int ks = 0; ks < 4; ++ks)
      a[ks] = *(const f16x8*)(cur + lm*XS + ks*32 + lk*8);

    // ---- MFMA: slot0 (and slot1 on wv2) ----
    f32x4 acc0[4];
    #pragma unroll
    for (int g = 0; g < 4; ++g) acc0[g] = (f32x4){bias0[g], bias0[g], bias0[g], bias0[g]};
    #pragma unroll
    for (int ks = 0; ks < 3; ++ks) {
      #pragma unroll
      for (int g = 0; g < 4; ++g)
        acc0[g] = __builtin_amdgcn_mfma_f32_16x16x32_f16(a[ks], WA[g][ks], acc0[g], 0, 0, 0);
    }
    if (isw3) {
      #pragma unroll
      for (int g = 0; g < 4; ++g)
        acc0[g] = __builtin_amdgcn_mfma_f32_16x16x32_f16(a[3], WA[g][3], acc0[g], 0, 0, 0);
    }

    f32x4 acc1[4];
    if (isw2) {
      #pragma unroll
      for (int g = 0; g < 4; ++g) acc1[g] = (f32x4){bias1[g], bias1[g], bias1[g], bias1[g]};
      #pragma unroll
      for (int j = 0; j < 3; ++j) {
        #pragma unroll
        for (int g = 0; g < 4; ++g)
          acc1[g] = __builtin_amdgcn_mfma_f32_16x16x32_f16(a[j+1], WB[g][j], acc1[g], 0, 0, 0);
      }
    }

    // ---- lane-local LSTM update, slot0 ----
    {
      const bool dm = isl2_0 ? (t >= 1) : (t < TT);
      #pragma unroll
      for (int m = 0; m < 4; ++m) {
        float ig = sigm  (acc0[0][m]);
        float fg = sigm  (acc0[1][m]);
        float cg = tanh_f(acc0[2][m]);
        float og = sigm  (acc0[3][m]);
        float cn = fg * c0[m] + ig * cg;
        float h  = og * tanh_f(cn);
        if (dm) {
          c0[m] = cn;
          nxt[(4*lk + m)*XS + dest0] = (_Float16)h;
        }
      }
    }

    // ---- slot1 update (wv2: L2 unit 14) ----
    if (isw2 && t >= 1) {
      #pragma unroll
      for (int m = 0; m < 4; ++m) {
        float ig = sigm  (acc1[0][m]);
        float fg = sigm  (acc1[1][m]);
        float cg = tanh_f(acc1[2][m]);
        float og = sigm  (acc1[3][m]);
        float cn = fg * c1[m] + ig * cg;
        c1[m] = cn;
        float h = og * tanh_f(cn);
        if (val1) nxt[(4*lk + m)*XS + 102] = (_Float16)h;
      }
    }

    // ---- stage x(t+1) into next buffer ----
    if (px) {
      nxt[lb0] = (_Float16)xr0;
      nxt[lb1] = (_Float16)xr1;
      if (v2) nxt[lb2] = (_Float16)xr2;
    }

    __syncthreads();
  }

  // ---- FC on h2(255) (in bufA[1], cols 88..102) ----
  if (tid < SB*NC) {
    int s = tid / NC, n = tid % NC;
    float acc = b_fc[n];
    #pragma unroll
    for (int u = 0; u < H2; ++u)
      acc += (float)bufA[1][s][88 + u] * w_fc[n*H2 + u];
    out[((size_t)blk*SB + s)*NC + n] = acc;
  }
}

extern "C" void kernel_launch(void* const* d_in, const int* in_sizes, int n_in,
                              void* d_out, int out_size, void* d_ws, size_t ws_size,
                              hipStream_t stream) {
  (void)n_in; (void)d_ws; (void)ws_size; (void)out_size;
  const float* x     = (const float*)d_in[0];
  const float* w_ih1 = (const float*)d_in[1];
  const float* w_hh1 = (const float*)d_in[2];
  const float* b_ih1 = (const float*)d_in[3];
  const float* b_hh1 = (const float*)d_in[4];
  const float* w_ih2 = (const float*)d_in[5];
  const float* w_hh2 = (const float*)d_in[6];
  const float* b_ih2 = (const float*)d_in[7];
  const float* b_hh2 = (const float*)d_in[8];
  const float* w_fc  = (const float*)d_in[9];
  const float* b_fc  = (const float*)d_in[10];
  float* out = (float*)d_out;

  const int B = in_sizes[0] / (TT * I1);   // 4096
  dim3 grid(B / SB), block(256);
  lstm2_fused<<<grid, block, 0, stream>>>(x, w_ih1, w_hh1, b_ih1, b_hh1,
                                          w_ih2, w_hh2, b_ih2, b_hh2,
                                          w_fc, b_fc, out);
}